// Round 2
// baseline (1252.881 us; speedup 1.0000x reference)
//
#include <hip/hip_runtime.h>
#include <cmath>

#define NROWS 65536
#define EDIM  1024
#define KST   4

// Barrier-free design: weights are tiny (44 KB/stage) and shared by all waves,
// so they live in L1/L2 — each wave loads its own fragments directly from
// global. No LDS staging, no per-stage __syncthreads, waves fully independent.
// q4 eliminated (q = h_in - r_final, h_in re-read in epilogue) to cut VGPRs.
__global__ __launch_bounds__(256, 3) void rvq_fused(
    const float* __restrict__ h_in,    // (N,1024)
    const float* __restrict__ W_proj,  // (4,5,1024)
    const float* __restrict__ b_proj,  // (4,5)
    const float* __restrict__ W_inv,   // (4,1024,5)
    const float* __restrict__ b_inv,   // (4,1024)
    const float* __restrict__ temp,    // (1)
    const float* __restrict__ u,       // (4,N,5,8)
    const float* __restrict__ p,       // (N)
    float* __restrict__ out_q,         // (N,1024)
    float* __restrict__ out_code,      // (N,20)
    float* __restrict__ out_loss,      // (1)
    float shift012, float shift3)
{
    __shared__ float sCode[4 * 80];    // 80 codes per wave, gathered then stored coalesced

    const int tid  = threadIdx.x;
    const int lane = tid & 63;
    const int wib  = tid >> 6;
    const int wid  = blockIdx.x * 4 + wib;
    const int row0 = wid * 4;           // 4 rows per wave

    // ---- lane-role constants (d,c) for gumbel/argmax; lanes 40..63 duplicate d=4 ----
    int dl = lane >> 3; if (dl > 4) dl = 4;
    const int   cl     = lane & 7;
    const float stepf  = (float)(cl - 4);
    const bool  valid  = (dl < 3) || (dl == 3 && cl >= 1 && cl <= 6)
                                  || (dl == 4 && cl >= 2 && cl <= 6);
    const float shiftd = (dl < 3) ? shift012 : ((dl == 3) ? shift3 : 0.0f);
    const float halfld = (dl < 3) ? 3.4965f : ((dl == 3) ? 2.4975f : 1.998f);
    const float offd   = (dl == 4) ? 0.0f : 0.5f;
    const float invhwd = (dl < 3) ? 0.25f : ((dl == 3) ? (1.0f/3.0f) : 0.5f);
    const int   ulane  = (lane < 40) ? lane : 39;

    const float tval = temp[0];                 // uniform -> SGPR
    const float te      = fmaxf(tval * tval, 1e-8f);
    const float inv_te  = 1.0f / te;
    const float alpham1 = inv_te - 1.0f;

    // ---- load rows (r starts as h_in) ----
    float4 r4[4][4];
    float  p_r[4];
    float  ss[4];
    #pragma unroll
    for (int rr = 0; rr < 4; ++rr) {
        const float4* src = (const float4*)(h_in + (size_t)(row0 + rr) * EDIM);
        #pragma unroll
        for (int j = 0; j < 4; ++j) r4[rr][j] = src[lane + 64 * j];
        p_r[rr] = p[row0 + rr];
        float s = 0.f;
        #pragma unroll
        for (int j = 0; j < 4; ++j) {
            s = fmaf(r4[rr][j].x, r4[rr][j].x, s);
            s = fmaf(r4[rr][j].y, r4[rr][j].y, s);
            s = fmaf(r4[rr][j].z, r4[rr][j].z, s);
            s = fmaf(r4[rr][j].w, r4[rr][j].w, s);
        }
        ss[rr] = (p_r[rr] <= 0.0f) ? s : 0.0f;   // p==0 edge: q_mix=0 -> ||h_in||
    }

    for (int i = 0; i < KST; ++i) {
        // ---- proj: h[d] = sum_e Wp[d][e] * r[e], Wp straight from global (L1-hot) ----
        const float4* wp4 = (const float4*)(W_proj + (size_t)i * 5120);
        float acc[5][4];
        #pragma unroll
        for (int d = 0; d < 5; ++d)
            #pragma unroll
            for (int rr = 0; rr < 4; ++rr) acc[d][rr] = 0.f;

        #pragma unroll
        for (int d = 0; d < 5; ++d) {
            #pragma unroll
            for (int j = 0; j < 4; ++j) {
                float4 w = wp4[d * 256 + lane + 64 * j];
                #pragma unroll
                for (int rr = 0; rr < 4; ++rr) {
                    float a = acc[d][rr];
                    a = fmaf(w.x, r4[rr][j].x, a);
                    a = fmaf(w.y, r4[rr][j].y, a);
                    a = fmaf(w.z, r4[rr][j].z, a);
                    a = fmaf(w.w, r4[rr][j].w, a);
                    acc[d][rr] = a;
                }
            }
        }
        #pragma unroll
        for (int d = 0; d < 5; ++d) {
            float bp = b_proj[i * 5 + d];        // uniform -> s_load
            #pragma unroll
            for (int rr = 0; rr < 4; ++rr) {
                float v = acc[d][rr];
                v += __shfl_xor(v, 1);
                v += __shfl_xor(v, 2);
                v += __shfl_xor(v, 4);
                v += __shfl_xor(v, 8);
                v += __shfl_xor(v, 16);
                v += __shfl_xor(v, 32);
                acc[d][rr] = v + bp;
            }
        }

        // ---- bound + gumbel-argmax, lanes act as (d,c) pairs ----
        float zq_mine[4];
        #pragma unroll
        for (int rr = 0; rr < 4; ++rr) {
            float hsel = acc[0][rr];
            hsel = (dl == 1) ? acc[1][rr] : hsel;
            hsel = (dl == 2) ? acc[2][rr] : hsel;
            hsel = (dl == 3) ? acc[3][rr] : hsel;
            hsel = (dl == 4) ? acc[4][rr] : hsel;
            float z  = __fsub_rn(__fmul_rn(tanhf(hsel + shiftd), halfld), offd);
            float uu = u[(size_t)i * 2621440 + (size_t)(row0 + rr) * 40 + ulane];
            float g1 = logf(uu + 1e-20f);
            float g  = -logf(-g1 + 1e-20f);
            float df = __fsub_rn(z, stepf);
            float d2 = __fmul_rn(df, df);
            d2 = valid ? d2 : 1e8f;
            float d2x = fmaf(alpham1, d2, d2);
            float y   = -(d2x * inv_te) + g;
            int   idx = cl;
            #pragma unroll
            for (int m = 1; m <= 4; m <<= 1) {   // argmax within 8-lane group, first-index ties
                float yo = __shfl_xor(y, m);
                int   io = __shfl_xor(idx, m);
                bool take = (yo > y) || (yo == y && io < idx);
                y   = take ? yo : y;
                idx = take ? io : idx;
            }
            zq_mine[rr] = (float)(idx - 4) * invhwd;
        }
        // stash codes in LDS (coalesced global store in epilogue)
        if (lane < 40 && cl == 0) {
            #pragma unroll
            for (int rr = 0; rr < 4; ++rr)
                sCode[wib * 80 + rr * 20 + i * 5 + dl] = zq_mine[rr];
        }
        // broadcast zq[d] to all lanes
        float zq[5][4];
        #pragma unroll
        for (int d = 0; d < 5; ++d)
            #pragma unroll
            for (int rr = 0; rr < 4; ++rr)
                zq[d][rr] = __shfl(zq_mine[rr], d * 8);

        // ---- inverse proj from global, no transpose needed in-register:
        //      qi[e] = b_inv[e] + sum_d zq[d] * W_inv[e][d] ----
        const float*  wi  = W_inv + (size_t)i * 5120;
        const float4* bi4 = (const float4*)(b_inv + (size_t)i * EDIM);
        #pragma unroll
        for (int j = 0; j < 4; ++j) {
            float4 b = bi4[lane + 64 * j];
            // 4 e-values (e0..e0+3) x 5 d-values = 20 consecutive floats
            const float4* wbase = (const float4*)(wi + (size_t)(4 * lane + 256 * j) * 5);
            float4 wv0 = wbase[0], wv1 = wbase[1], wv2 = wbase[2],
                   wv3 = wbase[3], wv4 = wbase[4];
            float wf[20];
            wf[0]=wv0.x; wf[1]=wv0.y; wf[2]=wv0.z; wf[3]=wv0.w;
            wf[4]=wv1.x; wf[5]=wv1.y; wf[6]=wv1.z; wf[7]=wv1.w;
            wf[8]=wv2.x; wf[9]=wv2.y; wf[10]=wv2.z; wf[11]=wv2.w;
            wf[12]=wv3.x; wf[13]=wv3.y; wf[14]=wv3.z; wf[15]=wv3.w;
            wf[16]=wv4.x; wf[17]=wv4.y; wf[18]=wv4.z; wf[19]=wv4.w;
            #pragma unroll
            for (int rr = 0; rr < 4; ++rr) {
                float qx = b.x, qy = b.y, qz = b.z, qw = b.w;
                #pragma unroll
                for (int d = 0; d < 5; ++d) {
                    float zd = zq[d][rr];
                    qx = fmaf(zd, wf[0 + d],  qx);
                    qy = fmaf(zd, wf[5 + d],  qy);
                    qz = fmaf(zd, wf[10 + d], qz);
                    qw = fmaf(zd, wf[15 + d], qw);
                }
                r4[rr][j].x -= qx;
                r4[rr][j].y -= qy;
                r4[rr][j].z -= qz;
                r4[rr][j].w -= qw;
            }
        }
        // ---- loss snapshot: ||r||^2 at the selected stage ----
        const float lo = i * 0.25f, hi = (i + 1) * 0.25f;
        #pragma unroll
        for (int rr = 0; rr < 4; ++rr) {
            if (lo < p_r[rr] && p_r[rr] <= hi) {
                float s = 0.f;
                #pragma unroll
                for (int j = 0; j < 4; ++j) {
                    s = fmaf(r4[rr][j].x, r4[rr][j].x, s);
                    s = fmaf(r4[rr][j].y, r4[rr][j].y, s);
                    s = fmaf(r4[rr][j].z, r4[rr][j].z, s);
                    s = fmaf(r4[rr][j].w, r4[rr][j].w, s);
                }
                ss[rr] = s;
            }
        }
    }

    // ---- epilogue: q = h_in - r (re-read h_in, mostly L3-hot), store coalesced ----
    #pragma unroll
    for (int rr = 0; rr < 4; ++rr) {
        const float4* src = (const float4*)(h_in + (size_t)(row0 + rr) * EDIM);
        float4* dst = (float4*)(out_q + (size_t)(row0 + rr) * EDIM);
        #pragma unroll
        for (int j = 0; j < 4; ++j) {
            float4 h0 = src[lane + 64 * j];
            float4 rv = r4[rr][j];
            dst[lane + 64 * j] = make_float4(h0.x - rv.x, h0.y - rv.y,
                                             h0.z - rv.z, h0.w - rv.w);
        }
    }

    // ---- codes: one barrier for the whole kernel, then coalesced store ----
    __syncthreads();
    {
        size_t base = (size_t)row0 * 20;
        out_code[base + lane] = sCode[wib * 80 + lane];
        if (lane < 16) out_code[base + 64 + lane] = sCode[wib * 80 + 64 + lane];
    }

    // ---- loss reduce ----
    float lsum = 0.f;
    #pragma unroll
    for (int rr = 0; rr < 4; ++rr) {
        float v = ss[rr];
        v += __shfl_xor(v, 1);
        v += __shfl_xor(v, 2);
        v += __shfl_xor(v, 4);
        v += __shfl_xor(v, 8);
        v += __shfl_xor(v, 16);
        v += __shfl_xor(v, 32);
        lsum += sqrtf(v);
    }
    if (lane == 0) atomicAdd(out_loss, lsum * (1.0f / 65536.0f));
}

extern "C" void kernel_launch(void* const* d_in, const int* in_sizes, int n_in,
                              void* d_out, int out_size, void* d_ws, size_t ws_size,
                              hipStream_t stream) {
    (void)in_sizes; (void)n_in; (void)out_size; (void)d_ws; (void)ws_size;
    const float* h_in   = (const float*)d_in[0];
    const float* W_proj = (const float*)d_in[1];
    const float* b_proj = (const float*)d_in[2];
    const float* W_inv  = (const float*)d_in[3];
    const float* b_inv  = (const float*)d_in[4];
    const float* temp   = (const float*)d_in[5];
    const float* u      = (const float*)d_in[6];
    const float* p      = (const float*)d_in[7];

    float* out_q    = (float*)d_out;
    float* out_code = out_q + (size_t)NROWS * EDIM;
    float* out_loss = out_code + (size_t)NROWS * 20;

    hipMemsetAsync(out_loss, 0, sizeof(float), stream);

    double hl01 = (8.0 - 1.0) * (1.0 - 1e-3) / 2.0;   // 3.4965
    double hl3  = (6.0 - 1.0) * (1.0 - 1e-3) / 2.0;   // 2.4975
    float shift012 = (float)std::tan(0.5 / hl01);
    float shift3   = (float)std::tan(0.5 / hl3);

    dim3 grid(NROWS / 16);   // 4 waves/block * 4 rows/wave
    dim3 block(256);
    hipLaunchKernelGGL(rvq_fused, grid, block, 0, stream,
                       h_in, W_proj, b_proj, W_inv, b_inv, temp, u, p,
                       out_q, out_code, out_loss, shift012, shift3);
}